// Round 2
// baseline (11415.031 us; speedup 1.0000x reference)
//
#include <hip/hip_runtime.h>
#include <cstdint>

#define BATCH 64
#define NODES 207
#define HID   64
#define NH    (NODES*HID)      // 13248
#define TOT   (BATCH*NH)       // 847872
#define NCOL  (BATCH*HID)      // 4096 columns in transposed [n, b*64+h] layout
#define ASTR  208              // padded A^T stride
#define NSTEPS 100

// ---------------- threefry2x32 (JAX partitionable semantics) ----------------
__device__ __forceinline__ uint32_t rotl32(uint32_t v, int n) {
    return (v << n) | (v >> (32 - n));
}

__device__ __forceinline__ void threefry2x32(uint32_t k0, uint32_t k1,
                                             uint32_t& x0, uint32_t& x1) {
    uint32_t ks0 = k0, ks1 = k1, ks2 = k0 ^ k1 ^ 0x1BD11BDAu;
    x0 += ks0; x1 += ks1;
#define TF_ROUND(r) { x0 += x1; x1 = rotl32(x1, (r)); x1 ^= x0; }
    TF_ROUND(13) TF_ROUND(15) TF_ROUND(26) TF_ROUND(6)
    x0 += ks1; x1 += ks2 + 1u;
    TF_ROUND(17) TF_ROUND(29) TF_ROUND(16) TF_ROUND(24)
    x0 += ks2; x1 += ks0 + 2u;
    TF_ROUND(13) TF_ROUND(15) TF_ROUND(26) TF_ROUND(6)
    x0 += ks0; x1 += ks1 + 3u;
    TF_ROUND(17) TF_ROUND(29) TF_ROUND(16) TF_ROUND(24)
    x0 += ks1; x1 += ks2 + 4u;
    TF_ROUND(13) TF_ROUND(15) TF_ROUND(26) TF_ROUND(6)
    x0 += ks2; x1 += ks0 + 5u;
#undef TF_ROUND
}

// ---------------- erfinv (XLA Giles poly, fast hw log) ----------------
__device__ __forceinline__ float erfinv32(float x) {
    // w = -log1p(-x*x); 1-x^2 >= 1.1e-7 given |x| <= 0.99999994, so direct
    // computation via v_log_f32 is safe (tail error ~1e-5 abs in the normal,
    // x0.001 into y -- negligible vs 2e-2 threshold).
    float w = -0.69314718056f * __builtin_amdgcn_logf(fmaf(-x, x, 1.0f));
    float p;
    if (w < 5.0f) {
        w = w - 2.5f;
        p =             2.81022636e-08f;
        p = fmaf(p, w,  3.43273939e-07f);
        p = fmaf(p, w, -3.5233877e-06f);
        p = fmaf(p, w, -4.39150654e-06f);
        p = fmaf(p, w,  0.00021858087f);
        p = fmaf(p, w, -0.00125372503f);
        p = fmaf(p, w, -0.00417768164f);
        p = fmaf(p, w,  0.246640727f);
        p = fmaf(p, w,  1.50140941f);
    } else {
        w = sqrtf(w) - 3.0f;
        p =            -0.000200214257f;
        p = fmaf(p, w,  0.000100950558f);
        p = fmaf(p, w,  0.00134934322f);
        p = fmaf(p, w, -0.00367342844f);
        p = fmaf(p, w,  0.00573950773f);
        p = fmaf(p, w, -0.0076224613f);
        p = fmaf(p, w,  0.00943887047f);
        p = fmaf(p, w,  1.00167406f);
        p = fmaf(p, w,  2.83297682f);
    }
    return p * x;
}

__device__ __forceinline__ float bits_to_normal(uint32_t bits) {
    uint32_t fb = (bits >> 9) | 0x3f800000u;
    float f = __uint_as_float(fb) - 1.0f;   // [0,1)
    const float lo = -0.99999994f;
    float u = f * 2.0f + lo;
    u = fmaxf(lo, u);
    return 1.41421356237f * erfinv32(u);
}

// tanh via hw exp2: err ~1e-6, saturates correctly at +-inf
__device__ __forceinline__ float fast_tanh(float x) {
    float e = __builtin_amdgcn_exp2f(x * 2.885390081777927f);  // 2x*log2(e)
    return 1.0f - 2.0f * __builtin_amdgcn_rcpf(e + 1.0f);
}

__device__ __forceinline__ float rl(float v, int k) {
    return __int_as_float(__builtin_amdgcn_readlane(__float_as_int(v), k));
}

// ---------------- kernels ----------------

// Build y0[n][b*64+h] (transposed from x[b][n][h]), A^T padded, step keys.
__global__ void k_init(const float* __restrict__ x, const float* __restrict__ A,
                       float* __restrict__ y0, float* __restrict__ At,
                       uint32_t* __restrict__ keys) {
    int tid = blockIdx.x * blockDim.x + threadIdx.x;
    int stride = gridDim.x * blockDim.x;
    int n4 = NODES * (NCOL / 4);            // 211968 float4 groups
    for (int i = tid; i < n4; i += stride) {
        int n = i >> 10, c4 = i & 1023;
        int c = c4 << 2, b = c >> 6, h = c & 63;
        ((float4*)y0)[i] = *((const float4*)(x + (size_t)b*NH + n*64 + h));
    }
    for (int i = tid; i < ASTR*ASTR; i += stride) {
        int n = i / ASTR, m = i - n*ASTR;
        At[i] = (n < NODES && m < NODES) ? A[m*NODES + n] : 0.0f;
    }
    if (tid < NSTEPS) {
        uint32_t x0 = 0u, x1 = (uint32_t)tid;
        threefry2x32(0u, 42u, x0, x1);
        keys[2*tid]   = x0;
        keys[2*tid+1] = x1;
    }
}

// One fused SDE step: AY = A@Y (stage1, A via scalar pipe), T/D GEMMs via
// readlane (stage2), noise + Euler-Maruyama update, write y_next.
// grid (13 m-tiles, 64 b), block 256 (4 waves x 4 rows each). Zero LDS.
__global__ __launch_bounds__(256) void k_fstep(
    const float* __restrict__ ycur, float* __restrict__ ynext,
    const float* __restrict__ At, const float* __restrict__ Wt,
    const float* __restrict__ bt, const float* __restrict__ Wd,
    const float* __restrict__ bd, const uint32_t* __restrict__ keys, int s)
{
    int lane = threadIdx.x & 63;
    int w    = __builtin_amdgcn_readfirstlane((int)(threadIdx.x >> 6));
    int mt   = blockIdx.x;                 // 0..12
    int b    = blockIdx.y;                 // 0..63
    int m0   = mt*16 + w*4;                // wave's rows m0..m0+3 (wave-uniform)
    int cb   = b*64 + lane;

    float acc[4] = {0.f, 0.f, 0.f, 0.f};
    // stage 1: acc[j] = sum_n At[n][m0+j] * y[n][cb]
    // A^T rows are 16B-aligned at m0 (mult of 4) -> scalar dwordx4 loads
    #pragma unroll 2
    for (int n = 0; n < NODES; ++n) {
        float yv = ycur[n*NCOL + cb];
        float4 a4 = *((const float4*)(At + n*ASTR + m0));
        acc[0] = fmaf(a4.x, yv, acc[0]);
        acc[1] = fmaf(a4.y, yv, acc[1]);
        acc[2] = fmaf(a4.z, yv, acc[2]);
        acc[3] = fmaf(a4.w, yv, acc[3]);
    }
    // stage 2: T/D rows via readlane broadcast of AY row (no memory round-trip)
    float t[4] = {0.f,0.f,0.f,0.f}, d[4] = {0.f,0.f,0.f,0.f};
    #pragma unroll 8
    for (int k = 0; k < 64; ++k) {
        float wt = Wt[k*64 + lane];
        float wd = Wd[k*64 + lane];
        #pragma unroll
        for (int j = 0; j < 4; ++j) {
            float sv = rl(acc[j], k);      // AY[m0+j][k]
            t[j] = fmaf(sv, wt, t[j]);
            d[j] = fmaf(sv, wd, d[j]);
        }
    }
    uint32_t k0 = keys[2*s], k1 = keys[2*s+1];
    float btl = bt[lane], bdl = bd[lane];
    #pragma unroll
    for (int j = 0; j < 4; ++j) {
        int m = m0 + j;
        if (m < NODES) {
            float F = 0.1f * fast_tanh(t[j] + btl);
            float G = 0.1f * fast_tanh(d[j] + bdl);
            uint32_t x0 = 0u, x1 = (uint32_t)(b*NH + m*64 + lane);
            threefry2x32(k0, k1, x0, x1);
            float nrm = bits_to_normal(x0 ^ x1);
            size_t idx = (size_t)m*NCOL + cb;
            ynext[idx] = (ycur[idx] + F * 0.01f) + (G * 0.1f) * nrm;
        }
    }
}

// out[(b*207+n)*4096 + c] = tanh(sum_h y[n][b*64+h] * Wo[h][c] + bo[c])
// grid (207, 4 b-groups, 4 col-kilogroups), block 256; wave = 16 rows x 256 cols.
__global__ __launch_bounds__(256) void k_out(
    const float* __restrict__ y, const float* __restrict__ Wo,
    const float* __restrict__ bo, float* __restrict__ out)
{
    int lane = threadIdx.x & 63;
    int w    = __builtin_amdgcn_readfirstlane((int)(threadIdx.x >> 6));
    int n    = blockIdx.x;                 // 0..206
    int bg   = blockIdx.y;                 // 0..3  (16 b's)
    int c0   = blockIdx.z * 1024 + w * 256;  // wave's 256 cols

    float yv[16];
    #pragma unroll
    for (int j = 0; j < 16; ++j)
        yv[j] = y[n*NCOL + (bg*16 + j)*64 + lane];

    float acc[4][16];
    #pragma unroll
    for (int q = 0; q < 4; ++q)
        #pragma unroll
        for (int j = 0; j < 16; ++j) acc[q][j] = 0.f;

    #pragma unroll 4
    for (int k = 0; k < 64; ++k) {
        float wo[4];
        #pragma unroll
        for (int q = 0; q < 4; ++q)
            wo[q] = Wo[(size_t)k*4096 + c0 + q*64 + lane];
        #pragma unroll
        for (int j = 0; j < 16; ++j) {
            float sv = rl(yv[j], k);       // y[n][b_j][h=k]
            #pragma unroll
            for (int q = 0; q < 4; ++q)
                acc[q][j] = fmaf(sv, wo[q], acc[q][j]);
        }
    }
    float bv[4];
    #pragma unroll
    for (int q = 0; q < 4; ++q) bv[q] = bo[c0 + q*64 + lane];
    #pragma unroll
    for (int j = 0; j < 16; ++j) {
        size_t ro = ((size_t)(bg*16 + j)*NODES + n)*4096 + c0 + lane;
        #pragma unroll
        for (int q = 0; q < 4; ++q)
            out[ro + q*64] = fast_tanh(acc[q][j] + bv[q]);
    }
}

extern "C" void kernel_launch(void* const* d_in, const int* in_sizes, int n_in,
                              void* d_out, int out_size, void* d_ws, size_t ws_size,
                              hipStream_t stream) {
    const float* x  = (const float*)d_in[0];
    const float* A  = (const float*)d_in[1];
    const float* Wt = (const float*)d_in[2];
    const float* bt = (const float*)d_in[3];
    const float* Wd = (const float*)d_in[4];
    const float* bd = (const float*)d_in[5];
    const float* Wo = (const float*)d_in[6];
    const float* bo = (const float*)d_in[7];
    float* out = (float*)d_out;

    float* y0 = (float*)d_ws;              // [207][4096]
    float* y1 = y0 + TOT;
    // A^T + keys live in the tail of d_out (217 MB); consumed before k_out
    // overwrites the full output at the end. Keeps ws usage == round 1's.
    float* At = out + (out_size - 65536);
    uint32_t* keys = (uint32_t*)(At + ASTR*ASTR);

    k_init<<<512, 256, 0, stream>>>(x, A, y0, At, keys);
    for (int s = 0; s < NSTEPS; ++s) {
        const float* src = (s & 1) ? y1 : y0;
        float*       dst = (s & 1) ? y0 : y1;
        k_fstep<<<dim3(13, 64), 256, 0, stream>>>(src, dst, At, Wt, bt, Wd, bd, keys, s);
    }
    // after 100 steps (even), final state is in y0
    k_out<<<dim3(207, 4, 4), 256, 0, stream>>>(y0, Wo, bo, out);
}